// Round 18
// baseline (87.302 us; speedup 1.0000x reference)
//
#include <hip/hip_runtime.h>

typedef unsigned long long u64;

constexpr int D = 48, H = 384, W = 384;
constexpr int WPR = 6;                    // 384 bits / 64 per row (real words)
constexpr int PADW = 8;                   // padded words per row: [pad, w0..w5, pad]
constexpr int NVOX = D * H * W;           // 7,077,888
constexpr int NWVOL = D * H * WPR;        // 110,592 packed words per volume
constexpr int MPAD2 = 52;                 // padded change-mask array (u64s)
constexpr int NXY = (D + 2) * PADW;       // padded words per xy slice = 400
constexpr int NTILE = D * 36;             // 1728 bit-transpose tiles (64x64)

// Banded z phase-A: dependency radius grows 1 row/subpass, so after KA
// subpasses the BAND-row core (with HALO>=KA halo rows) is exact.
constexpr int BAND = 96;
constexpr int HALO = 16;
constexpr int KA = 16;                    // even -> parity preserved for phase-B
constexpr int BROWS = BAND + 2 * HALO;    // 128 loaded rows
constexpr int NBAND = H / BAND;           // 4

// full adder: s = a+b+c (bit-sliced), cy = carry
__device__ __forceinline__ void fa(u64 a, u64 b, u64 c, u64& s, u64& cy) {
  u64 x = a ^ b;
  s = x ^ c;
  cy = (a & b) | (c & x);
}

// One Zhang-Suen subiteration for one packed word, all neighbors in registers.
__device__ __forceinline__ u64 zs_regs(u64 w00, u64 w01, u64 w02,
                                       u64 w10, u64 w11, u64 w12,
                                       u64 w20, u64 w21, u64 w22, bool first) {
  const u64 P2 = w01;                          // N
  const u64 P3 = (w01 >> 1) | (w02 << 63);     // NE
  const u64 P4 = (w11 >> 1) | (w12 << 63);     // E
  const u64 P5 = (w21 >> 1) | (w22 << 63);     // SE
  const u64 P6 = w21;                          // S
  const u64 P7 = (w21 << 1) | (w20 >> 63);     // SW
  const u64 P8 = (w11 << 1) | (w10 >> 63);     // W
  const u64 P9 = (w01 << 1) | (w00 >> 63);     // NW

  u64 s1, c1, s2, c2, s3, c3, u0, u1, v1, v2;
  fa(P2, P3, P4, s1, c1);
  fa(P5, P6, P7, s2, c2);
  fa(P8, P9, 0ull, s3, c3);
  fa(s1, s2, s3, u0, u1);
  fa(c1, c2, c3, v1, v2);
  u64 b1 = u1 ^ v1, k2 = u1 & v1;
  u64 b2 = v2 ^ k2, b3 = v2 & k2;
  u64 condB = (b1 | b2 | b3) & ~(b3 | (b2 & b1 & u0));   // 2<=B<=6

  u64 t0 = ~P2 & P3, t1 = ~P3 & P4, t2 = ~P4 & P5, t3 = ~P5 & P6;
  u64 t4 = ~P6 & P7, t5 = ~P7 & P8, t6 = ~P8 & P9, t7 = ~P9 & P2;
  fa(t0, t1, t2, s1, c1);
  fa(t3, t4, t5, s2, c2);
  fa(t6, t7, 0ull, s3, c3);
  fa(s1, s2, s3, u0, u1);
  fa(c1, c2, c3, v1, v2);
  u64 a1 = u1 ^ v1, j2 = u1 & v1;
  u64 a2 = v2 ^ j2, a3 = v2 & j2;
  u64 condA = u0 & ~(a1 | a2 | a3);                      // A == 1

  u64 cc = first ? ((~(P2 & P4 & P6)) & (~(P4 & P6 & P8)))
                 : ((~(P2 & P4 & P8)) & (~(P2 & P6 & P8)));
  return w11 & ~(condB & condA & cc);
}

// Wave-frame dirty test (see R13 derivation; bit l = dirty for word wb+l).
__device__ __forceinline__ u64 dirty_wave(const u64* __restrict__ U, int mw) {
  const u64 A = U[mw - 1], B = U[mw], C = U[mw + 1], Dw = U[mw + 2];
  const u64 smA = A | (A >> 1 | B << 63) | (A >> 2 | B << 62);
  const u64 smB = B | (B >> 1 | C << 63) | (B >> 2 | C << 62);
  const u64 smC = C | (C >> 1 | Dw << 63) | (C >> 2 | Dw << 62);
  const u64 Dm9 = (smB << 9) | (smA >> 55);
  const u64 Dm1 = (smB << 1) | (smA >> 63);
  const u64 Dp7 = (smB >> 7) | (smC << 57);
  return Dm9 | Dm1 | Dp7;
}

// One pruned subiteration pass over a padded (R+2) x 8 slice in LDS.
// Clean words fully skipped (dst holds the value from two passes ago).
template<int R, bool FIRST, int NTHR>
__device__ __forceinline__ void subpass(const u64* __restrict__ src, u64* __restrict__ dst,
                                        u64* rawW, const u64* rawPrev,
                                        u64* Uw, const u64* Ur,
                                        int* chgflag, int tid) {
  constexpr int NP = (R + 2) * PADW;
  int anych = 0;
  for (int base = 0; base < NP; base += NTHR) {
    const int idx = base + tid;
    int changed = 0;
    if (idx < NP) {
      const int mw = 1 + (idx >> 6);
      const u64 dmask = dirty_wave(Ur, mw);      // wave-uniform mask words
      if ((dmask >> (idx & 63)) & 1ull) {
        const u64 old = src[idx];
        u64 nw = 0;
        if (old) {
          nw = zs_regs(src[idx - PADW - 1], src[idx - PADW], src[idx - PADW + 1],
                       src[idx - 1], old, src[idx + 1],
                       src[idx + PADW - 1], src[idx + PADW], src[idx + PADW + 1], FIRST);
          changed = (nw != old);
        }
        dst[idx] = nw;
        anych |= changed;
      }
    }
    const u64 bal = __ballot(changed != 0);
    if ((tid & 63) == 0 && idx < NP) {
      const int mw = 1 + (idx >> 6);
      rawW[mw] = bal;
      Uw[mw] = bal | rawPrev[mw];
    }
  }
  if (anych) *chgflag = 1;
}

template<int MW, int NTHR>
__device__ __forceinline__ void init_masks(u64 (*raw)[MPAD2], u64 (*Um)[MPAD2], int tid) {
  for (int t = tid; t < 4 * MPAD2; t += NTHR) {
    const int arr = t / MPAD2, j = t - arr * MPAD2;
    const u64 v = ((arr & 1) && j >= 1 && j <= MW) ? ~0ull : 0ull;
    if (arr < 2) raw[arr][j] = v; else Um[arr - 2][j] = v;
  }
}

// Dense xy subpass: 512 threads, 400 words -> single trip.
template<bool FIRST>
__device__ __forceinline__ void xy_dense(const u64* __restrict__ src, u64* __restrict__ dst,
                                         int* chgflag, int tid) {
  int anych = 0;
  if (tid < NXY) {
    const u64 old = src[tid];
    u64 nw = 0;
    if (old) {
      nw = zs_regs(src[tid - PADW - 1], src[tid - PADW], src[tid - PADW + 1],
                   src[tid - 1], old, src[tid + 1],
                   src[tid + PADW - 1], src[tid + PADW], src[tid + PADW + 1], FIRST);
      anych = (nw != old);
    }
    dst[tid] = nw;
  }
  if (anych) *chgflag = 1;
}

// Phase-A band (512 threads): exactly KA subpasses; exact BAND-row core ->
// curZ. Exports final change masks (cm[KA], cm[KA]|cm[KA-1]) for core rows:
// global mask word jj (logical, 8 rows each) aligns with band mask words at
// an exact word offset (g0*8 is a multiple of 64). Straddle words: jj=12b
// excludes bits 0..7 (row 96b-1, prev band's core), jj=12b+12 keeps only
// bits 0..7 (row 96b+95).
__device__ __forceinline__ void band_body(const u64* __restrict__ maskP,
                                          u64* __restrict__ curZ,
                                          u64* __restrict__ expRaw,
                                          u64* __restrict__ expUm,
                                          int zi, int band, u64* Abuf, u64* Bbuf,
                                          u64 (*raw)[MPAD2], u64 (*Um)[MPAD2],
                                          int* s_chg) {
  constexpr int NP = (BROWS + 2) * PADW;   // 1040
  constexpr int MW = (NP + 63) >> 6;       // 17
  const int tid = threadIdx.x;
  const int g0 = band * BAND - HALO;       // global row of rp==1

  for (int idx = tid; idx < NP; idx += 512) {
    const int rp = idx >> 3, cp = idx & 7;
    const int g = g0 + rp - 1;
    u64 v = 0;
    if (rp >= 1 && rp <= BROWS && cp >= 1 && cp <= 6 && g >= 0 && g < H)
      v = maskP[(zi * H + g) * WPR + (cp - 1)];
    Abuf[idx] = v;
    Bbuf[idx] = 0;
  }
  init_masks<MW, 512>(raw, Um, tid);
  if (tid == 0) s_chg[0] = 0;
  __syncthreads();

  for (int t = 0; t < KA; t += 2) {
    subpass<BROWS, true, 512 >(Abuf, Bbuf, raw[0], raw[1], Um[0], Um[1], &s_chg[0], tid);
    __syncthreads();
    subpass<BROWS, false, 512>(Bbuf, Abuf, raw[1], raw[0], Um[1], Um[0], &s_chg[0], tid);
    __syncthreads();
  }
  // after loop: raw[1] = cm[KA], Um[1] = cm[KA] | cm[KA-1]; both exact on core.

  for (int idx = tid; idx < NP; idx += 512) {
    const int rp = idx >> 3, cp = idx & 7;
    if (rp < 1 || rp > BROWS || cp < 1 || cp > 6) continue;
    const int g = g0 + rp - 1;
    if (g < band * BAND || g >= band * BAND + BAND) continue;
    curZ[(zi * H + g) * WPR + (cp - 1)] = Abuf[idx];
  }

  // export masks: 13 logical global words jj = 12*band + t, band array word
  // bmw = t + 3 (offset = 2 - 12*band applied; verified word-aligned).
  if (tid < 13) {
    const int bmw = tid + 3;
    u64 m = ~0ull;
    if (tid == 0) m = ~0xFFull;
    else if (tid == 12) m = 0xFFull;
    const int eb = (zi * NBAND + band) * 16 + tid;
    expRaw[eb] = raw[1][bmw] & m;
    expUm[eb]  = Um[1][bmw] & m;
  }
}

// xy-slice thinning to convergence (dense, 512 threads), coalesced loads.
// MODE 1: slice=y (rows=z, cols=x), from maskP  -> skelY[(z*H+y)*WPR+xw]
// MODE 2: slice=x (rows=z, cols=y), from maskPX -> skelX[(z*W+x)*WPR+yw]
template<int MODE>
__device__ __forceinline__ void thin_xy(const u64* __restrict__ srcBuf,
                                        u64* __restrict__ dstBuf,
                                        int slice, u64* Abuf, u64* Bbuf,
                                        int* s_chg) {
  const int tid = threadIdx.x;
  constexpr int S = (MODE == 1) ? H : W;   // row stride multiplier

  if (tid < NXY) {
    const int rp = tid >> 3, cp = tid & 7;
    u64 v = 0;
    if (rp >= 1 && rp <= D && cp >= 1 && cp <= 6)
      v = srcBuf[((rp - 1) * S + slice) * WPR + (cp - 1)];
    Abuf[tid] = v;
    Bbuf[tid] = 0;
  }
  if (tid < 2) s_chg[tid] = 0;
  __syncthreads();

  int k = 0;
  while (true) {
    xy_dense<true >(Abuf, Bbuf, &s_chg[k], tid);
    __syncthreads();
    if (tid == 0) s_chg[k ^ 1] = 0;
    xy_dense<false>(Bbuf, Abuf, &s_chg[k], tid);
    __syncthreads();
    if (s_chg[k] == 0) break;
    k ^= 1;
  }

  if (tid < NXY) {
    const int rp = tid >> 3, cp = tid & 7;
    if (rp >= 1 && rp <= D && cp >= 1 && cp <= 6)
      dstBuf[((rp - 1) * S + slice) * WPR + (cp - 1)] = Abuf[tid];
  }
}

// K2 (512-thread blocks): b<192 -> z band phase-A; 192..575 -> x; else y.
__global__ __launch_bounds__(512) void thin_bands_xy(const u64* __restrict__ maskP,
                                                     const u64* __restrict__ maskPX,
                                                     u64* __restrict__ skelY,
                                                     u64* __restrict__ skelX,
                                                     u64* __restrict__ curZ,
                                                     u64* __restrict__ expRaw,
                                                     u64* __restrict__ expUm) {
  __shared__ u64 Abuf[(BROWS + 2) * PADW];   // 8.3 KB; xy paths use first 400
  __shared__ u64 Bbuf[(BROWS + 2) * PADW];
  __shared__ u64 raw[2][MPAD2];
  __shared__ u64 Um[2][MPAD2];
  __shared__ int s_chg[2];
  const int b = blockIdx.x;
  if (b < D * NBAND) {
    band_body(maskP, curZ, expRaw, expUm, b >> 2, b & 3, Abuf, Bbuf, raw, Um, s_chg);
  } else if (b < D * NBAND + W) {
    thin_xy<2>(maskPX, skelX, b - D * NBAND, Abuf, Bbuf, s_chg);
  } else {
    thin_xy<1>(maskP, skelY, b - D * NBAND - W, Abuf, Bbuf, s_chg);
  }
}

// K3: b<48 -> z phase-B from curZ, SEEDED with exact band change masks
// (no forced-dense passes). Bbuf initialized = Abuf = S_KA: a word clean at
// subpass KA+1 has S_{KA+1}(w) = S_{KA-1}(w) = S_KA(w) (w itself unchanged
// at KA, KA-1), so the skipped dst value is correct; thereafter the standard
// two-buffer invariant holds. Parity: KA even -> first phase-B subpass is
// first-type.  b>=48 -> skelX->skelXT ballot-transpose tiles.
__global__ __launch_bounds__(1024) void thin_z_finish(const u64* __restrict__ curZ,
                                                      u64* __restrict__ skelZ,
                                                      const u64* __restrict__ skelX,
                                                      u64* __restrict__ skelXT,
                                                      const u64* __restrict__ expRaw,
                                                      const u64* __restrict__ expUm) {
  __shared__ u64 Abuf[(H + 2) * PADW];
  __shared__ u64 Bbuf[(H + 2) * PADW];
  __shared__ u64 raw[2][MPAD2];
  __shared__ u64 Um[2][MPAD2];
  __shared__ int s_chg[2];
  const int b = blockIdx.x;
  const int tid = threadIdx.x;

  if (b < D) {
    constexpr int NP = (H + 2) * PADW;
    for (int idx = tid; idx < NP; idx += 1024) {
      const int rp = idx >> 3, cp = idx & 7;
      u64 v = 0;
      if (rp >= 1 && rp <= H && cp >= 1 && cp <= 6)
        v = curZ[(b * H + (rp - 1)) * WPR + (cp - 1)];
      Abuf[idx] = v;
      Bbuf[idx] = v;                       // MUST equal Abuf (see header comment)
    }
    // seed masks from band exports; logical word jj = j-1; main band jj/12,
    // straddle words (jj%12==0, jj>0) also OR prev band's word 12.
    if (tid < MPAD2) {
      const int j = tid, jj = j - 1;
      u64 r = 0, u = 0;
      if (jj >= 0 && jj <= 48) {
        const int bb = jj / 12, off = jj - 12 * bb;
        if (bb < NBAND) {
          r = expRaw[(b * NBAND + bb) * 16 + off];
          u = expUm[(b * NBAND + bb) * 16 + off];
        }
        if (off == 0 && jj > 0) {
          r |= expRaw[(b * NBAND + (jj / 12 - 1)) * 16 + 12];
          u |= expUm[(b * NBAND + (jj / 12 - 1)) * 16 + 12];
        }
      }
      raw[1][j] = r; Um[1][j] = u;
      raw[0][j] = 0; Um[0][j] = 0;
    }
    if (tid < 2) s_chg[tid] = 0;
    __syncthreads();

    int k = 0;
    while (true) {
      subpass<H, true, 1024 >(Abuf, Bbuf, raw[0], raw[1], Um[0], Um[1], &s_chg[k], tid);
      __syncthreads();
      if (tid == 0) s_chg[k ^ 1] = 0;
      subpass<H, false, 1024>(Bbuf, Abuf, raw[1], raw[0], Um[1], Um[0], &s_chg[k], tid);
      __syncthreads();
      if (s_chg[k] == 0) break;
      k ^= 1;
    }

    for (int idx = tid; idx < NP; idx += 1024) {
      const int rp = idx >> 3, cp = idx & 7;
      if (rp < 1 || rp > H || cp < 1 || cp > 6) continue;
      skelZ[(b * H + (rp - 1)) * WPR + (cp - 1)] = Abuf[idx];
    }
  } else {
    const int gw = (b - D) * 16 + (tid >> 6);   // tile id
    if (gw < NTILE) {
      const int lane = tid & 63;
      const int z = gw / 36, rem = gw - z * 36;
      const int yw = rem / 6, xw = rem - yw * 6;
      const int x = xw * 64 + lane;
      const u64 wx = skelX[(z * W + x) * WPR + yw];     // bits indexed by y
      u64 mine = 0;
      #pragma unroll 8
      for (int j = 0; j < 64; ++j) {
        u64 wj = __ballot((wx >> j) & 1ull);
        if (lane == j) mine = wj;
      }
      const int y = yw * 64 + lane;
      skelXT[(z * H + y) * WPR + xw] = mine;            // exclusive full coverage
    }
  }
}

// Fused pack + input transpose: 288 blocks = 48 z-slices x 6 row-chunks of 64.
// Packs its 64 rows into LDS + maskP, then transposes its 6 tiles -> maskPX.
__global__ __launch_bounds__(256) void init_pack_tr(const float* __restrict__ in,
                                                    u64* __restrict__ maskP,
                                                    u64* __restrict__ maskPX) {
  __shared__ u64 lds[64 * WPR];            // 384 words
  const int z = blockIdx.x / 6, yc = blockIdx.x % 6;
  const int lane = threadIdx.x & 63, wave = threadIdx.x >> 6;   // 4 waves
  for (int w = wave; w < 64 * WPR; w += 4) {
    const int yl = w / WPR, cp = w - yl * WPR;
    const int y = yc * 64 + yl;
    const size_t base = ((size_t)(z * H + y) * WPR + cp) * 64;
    const float v = in[base + lane];
    const u64 bits = __ballot(v == 1.0f);
    if (lane == 0) { lds[w] = bits; maskP[(z * H + y) * WPR + cp] = bits; }
  }
  __syncthreads();
  for (int xw = wave; xw < WPR; xw += 4) {
    const u64 wp = lds[lane * WPR + xw];   // row y=yc*64+lane, bits indexed by x
    u64 mine = 0;
    #pragma unroll 8
    for (int i = 0; i < 64; ++i) {
      u64 wi = __ballot((wp >> i) & 1ull); // bit l = pixel(y=yc*64+l, x=xw*64+i)
      if (lane == i) mine = wi;
    }
    maskPX[(z * W + xw * 64 + lane) * WPR + yc] = mine;
  }
}

// 6-connected dilation of (skelZ | skelY | skelXT) + mask + coalesced float4
// expansion. One block = 64 words = 4096 voxels.
__global__ __launch_bounds__(256) void dilate_expand(const u64* __restrict__ maskP,
                                                     const u64* __restrict__ sZ,
                                                     const u64* __restrict__ sY,
                                                     const u64* __restrict__ sXT,
                                                     float* __restrict__ out) {
  __shared__ u64 rw[64];
  const int tid = threadIdx.x;
  const int wbase = blockIdx.x * 64;
  if (tid < 64) {
    const int wi = wbase + tid;
    const int wc = wi % WPR;
    const int row = wi / WPR;        // row = z*H + y
    const int y = row % H;
    const int z = row / H;
    const u64 S = sZ[wi] | sY[wi] | sXT[wi];
    const u64 L = (wc > 0) ? (sZ[wi - 1] | sY[wi - 1] | sXT[wi - 1]) : 0ull;
    const u64 Rw = (wc < WPR - 1) ? (sZ[wi + 1] | sY[wi + 1] | sXT[wi + 1]) : 0ull;
    u64 d = S | (S << 1) | (L >> 63) | (S >> 1) | (Rw << 63);
    if (y > 0)     d |= sZ[wi - WPR] | sY[wi - WPR] | sXT[wi - WPR];
    if (y < H - 1) d |= sZ[wi + WPR] | sY[wi + WPR] | sXT[wi + WPR];
    if (z > 0)     d |= sZ[wi - H * WPR] | sY[wi - H * WPR] | sXT[wi - H * WPR];
    if (z < D - 1) d |= sZ[wi + H * WPR] | sY[wi + H * WPR] | sXT[wi + H * WPR];
    rw[tid] = d & maskP[wi];
  }
  __syncthreads();
  float4* o4 = reinterpret_cast<float4*>(out + (size_t)wbase * 64);
  #pragma unroll
  for (int k = 0; k < 4; ++k) {
    const int f = tid + 256 * k;
    const u64 bits = rw[f >> 4] >> ((f & 15) * 4);
    float4 o;
    o.x = (float)(bits & 1ull);
    o.y = (float)((bits >> 1) & 1ull);
    o.z = (float)((bits >> 2) & 1ull);
    o.w = (float)((bits >> 3) & 1ull);
    o4[f] = o;
  }
}

extern "C" void kernel_launch(void* const* d_in, const int* in_sizes, int n_in,
                              void* d_out, int out_size, void* d_ws, size_t ws_size,
                              hipStream_t stream) {
  const float* in = (const float*)d_in[0];
  float* out = (float*)d_out;
  u64* wsw = (u64*)d_ws;                 // 7*NWVOL + 2*192*16 u64 = 6.24 MB
  u64* maskP = wsw;
  u64* maskPX = wsw + NWVOL;
  u64* skelZ = wsw + 2 * NWVOL;
  u64* skelY = wsw + 3 * NWVOL;
  u64* skelX = wsw + 4 * NWVOL;
  u64* skelXT = wsw + 5 * NWVOL;
  u64* curZ = wsw + 6 * NWVOL;
  u64* expRaw = wsw + 7 * NWVOL;
  u64* expUm = expRaw + 192 * 16;

  init_pack_tr<<<D * 6, 256, 0, stream>>>(in, maskP, maskPX);
  thin_bands_xy<<<D * NBAND + W + H, 512, 0, stream>>>(maskP, maskPX, skelY, skelX,
                                                       curZ, expRaw, expUm);
  thin_z_finish<<<D + (NTILE + 15) / 16, 1024, 0, stream>>>(curZ, skelZ, skelX, skelXT,
                                                            expRaw, expUm);
  dilate_expand<<<NWVOL / 64, 256, 0, stream>>>(maskP, skelZ, skelY, skelXT, out);
}

// Round 19
// 58.015 us; speedup vs baseline: 1.5048x; 1.5048x over previous
//
#include <hip/hip_runtime.h>

typedef unsigned long long u64;

constexpr int D = 48, H = 384, W = 384;
constexpr int WPR = 6;                    // 384 bits / 64 per row (real words)
constexpr int PADW = 8;                   // padded words per row: [pad, w0..w5, pad]
constexpr int NVOX = D * H * W;           // 7,077,888
constexpr int NWVOL = D * H * WPR;        // 110,592 packed words per volume
constexpr int MPAD2 = 52;                 // padded change-mask array (u64s)
constexpr int NXY = (D + 2) * PADW;       // padded words per xy slice = 400
constexpr int NTILE = D * 36;             // 1728 bit-transpose tiles (64x64)

// Banded z phase-A: dependency radius grows 1 row/subpass, so after KA
// subpasses the BAND-row core (with HALO>=KA halo rows) is exact.
constexpr int BAND = 96;
constexpr int HALO = 16;
constexpr int KA = 16;                    // even -> parity preserved for phase-B
constexpr int BROWS = BAND + 2 * HALO;    // 128 loaded rows
constexpr int NBAND = H / BAND;           // 4

// full adder: s = a+b+c (bit-sliced), cy = carry
__device__ __forceinline__ void fa(u64 a, u64 b, u64 c, u64& s, u64& cy) {
  u64 x = a ^ b;
  s = x ^ c;
  cy = (a & b) | (c & x);
}

// One Zhang-Suen subiteration for one packed word, all neighbors in registers.
__device__ __forceinline__ u64 zs_regs(u64 w00, u64 w01, u64 w02,
                                       u64 w10, u64 w11, u64 w12,
                                       u64 w20, u64 w21, u64 w22, bool first) {
  const u64 P2 = w01;                          // N
  const u64 P3 = (w01 >> 1) | (w02 << 63);     // NE
  const u64 P4 = (w11 >> 1) | (w12 << 63);     // E
  const u64 P5 = (w21 >> 1) | (w22 << 63);     // SE
  const u64 P6 = w21;                          // S
  const u64 P7 = (w21 << 1) | (w20 >> 63);     // SW
  const u64 P8 = (w11 << 1) | (w10 >> 63);     // W
  const u64 P9 = (w01 << 1) | (w00 >> 63);     // NW

  u64 s1, c1, s2, c2, s3, c3, u0, u1, v1, v2;
  fa(P2, P3, P4, s1, c1);
  fa(P5, P6, P7, s2, c2);
  fa(P8, P9, 0ull, s3, c3);
  fa(s1, s2, s3, u0, u1);
  fa(c1, c2, c3, v1, v2);
  u64 b1 = u1 ^ v1, k2 = u1 & v1;
  u64 b2 = v2 ^ k2, b3 = v2 & k2;
  u64 condB = (b1 | b2 | b3) & ~(b3 | (b2 & b1 & u0));   // 2<=B<=6

  u64 t0 = ~P2 & P3, t1 = ~P3 & P4, t2 = ~P4 & P5, t3 = ~P5 & P6;
  u64 t4 = ~P6 & P7, t5 = ~P7 & P8, t6 = ~P8 & P9, t7 = ~P9 & P2;
  fa(t0, t1, t2, s1, c1);
  fa(t3, t4, t5, s2, c2);
  fa(t6, t7, 0ull, s3, c3);
  fa(s1, s2, s3, u0, u1);
  fa(c1, c2, c3, v1, v2);
  u64 a1 = u1 ^ v1, j2 = u1 & v1;
  u64 a2 = v2 ^ j2, a3 = v2 & j2;
  u64 condA = u0 & ~(a1 | a2 | a3);                      // A == 1

  u64 cc = first ? ((~(P2 & P4 & P6)) & (~(P4 & P6 & P8)))
                 : ((~(P2 & P4 & P8)) & (~(P2 & P6 & P8)));
  return w11 & ~(condB & condA & cc);
}

// Wave-frame dirty test (see R13 derivation; bit l = dirty for word wb+l).
__device__ __forceinline__ u64 dirty_wave(const u64* __restrict__ U, int mw) {
  const u64 A = U[mw - 1], B = U[mw], C = U[mw + 1], Dw = U[mw + 2];
  const u64 smA = A | (A >> 1 | B << 63) | (A >> 2 | B << 62);
  const u64 smB = B | (B >> 1 | C << 63) | (B >> 2 | C << 62);
  const u64 smC = C | (C >> 1 | Dw << 63) | (C >> 2 | Dw << 62);
  const u64 Dm9 = (smB << 9) | (smA >> 55);
  const u64 Dm1 = (smB << 1) | (smA >> 63);
  const u64 Dp7 = (smB >> 7) | (smC << 57);
  return Dm9 | Dm1 | Dp7;
}

// One pruned subiteration pass over a padded (R+2) x 8 slice in LDS.
// Clean words fully skipped (dst holds the value from two passes ago).
template<int R, bool FIRST, int NTHR>
__device__ __forceinline__ void subpass(const u64* __restrict__ src, u64* __restrict__ dst,
                                        u64* rawW, const u64* rawPrev,
                                        u64* Uw, const u64* Ur,
                                        int* chgflag, int tid) {
  constexpr int NP = (R + 2) * PADW;
  int anych = 0;
  for (int base = 0; base < NP; base += NTHR) {
    const int idx = base + tid;
    int changed = 0;
    if (idx < NP) {
      const int mw = 1 + (idx >> 6);
      const u64 dmask = dirty_wave(Ur, mw);      // wave-uniform mask words
      if ((dmask >> (idx & 63)) & 1ull) {
        const u64 old = src[idx];
        u64 nw = 0;
        if (old) {
          nw = zs_regs(src[idx - PADW - 1], src[idx - PADW], src[idx - PADW + 1],
                       src[idx - 1], old, src[idx + 1],
                       src[idx + PADW - 1], src[idx + PADW], src[idx + PADW + 1], FIRST);
          changed = (nw != old);
        }
        dst[idx] = nw;
        anych |= changed;
      }
    }
    const u64 bal = __ballot(changed != 0);
    if ((tid & 63) == 0 && idx < NP) {
      const int mw = 1 + (idx >> 6);
      rawW[mw] = bal;
      Uw[mw] = bal | rawPrev[mw];
    }
  }
  if (anych) *chgflag = 1;
}

template<int MW, int NTHR>
__device__ __forceinline__ void init_masks(u64 (*raw)[MPAD2], u64 (*Um)[MPAD2], int tid) {
  for (int t = tid; t < 4 * MPAD2; t += NTHR) {
    const int arr = t / MPAD2, j = t - arr * MPAD2;
    const u64 v = ((arr & 1) && j >= 1 && j <= MW) ? ~0ull : 0ull;
    if (arr < 2) raw[arr][j] = v; else Um[arr - 2][j] = v;
  }
}

// Dense xy subpass: 512 threads, 400 words -> single trip.
template<bool FIRST>
__device__ __forceinline__ void xy_dense(const u64* __restrict__ src, u64* __restrict__ dst,
                                         int* chgflag, int tid) {
  int anych = 0;
  if (tid < NXY) {
    const u64 old = src[tid];
    u64 nw = 0;
    if (old) {
      nw = zs_regs(src[tid - PADW - 1], src[tid - PADW], src[tid - PADW + 1],
                   src[tid - 1], old, src[tid + 1],
                   src[tid + PADW - 1], src[tid + PADW], src[tid + PADW + 1], FIRST);
      anych = (nw != old);
    }
    dst[tid] = nw;
  }
  if (anych) *chgflag = 1;
}

// Phase-A band (512 threads): exactly KA subpasses; exact BAND-row core ->
// curZ. Exports final change masks (cm[KA], cm[KA]|cm[KA-1]) for core rows.
__device__ __forceinline__ void band_body(const u64* __restrict__ maskP,
                                          u64* __restrict__ curZ,
                                          u64* __restrict__ expRaw,
                                          u64* __restrict__ expUm,
                                          int zi, int band, u64* Abuf, u64* Bbuf,
                                          u64 (*raw)[MPAD2], u64 (*Um)[MPAD2],
                                          int* s_chg) {
  constexpr int NP = (BROWS + 2) * PADW;   // 1040
  constexpr int MW = (NP + 63) >> 6;       // 17
  const int tid = threadIdx.x;
  const int g0 = band * BAND - HALO;       // global row of rp==1

  for (int idx = tid; idx < NP; idx += 512) {
    const int rp = idx >> 3, cp = idx & 7;
    const int g = g0 + rp - 1;
    u64 v = 0;
    if (rp >= 1 && rp <= BROWS && cp >= 1 && cp <= 6 && g >= 0 && g < H)
      v = maskP[(zi * H + g) * WPR + (cp - 1)];
    Abuf[idx] = v;
    Bbuf[idx] = 0;
  }
  init_masks<MW, 512>(raw, Um, tid);
  if (tid == 0) s_chg[0] = 0;
  __syncthreads();

  for (int t = 0; t < KA; t += 2) {
    subpass<BROWS, true, 512 >(Abuf, Bbuf, raw[0], raw[1], Um[0], Um[1], &s_chg[0], tid);
    __syncthreads();
    subpass<BROWS, false, 512>(Bbuf, Abuf, raw[1], raw[0], Um[1], Um[0], &s_chg[0], tid);
    __syncthreads();
  }
  // after loop: raw[1] = cm[KA], Um[1] = cm[KA] | cm[KA-1]; both exact on core.

  for (int idx = tid; idx < NP; idx += 512) {
    const int rp = idx >> 3, cp = idx & 7;
    if (rp < 1 || rp > BROWS || cp < 1 || cp > 6) continue;
    const int g = g0 + rp - 1;
    if (g < band * BAND || g >= band * BAND + BAND) continue;
    curZ[(zi * H + g) * WPR + (cp - 1)] = Abuf[idx];
  }

  // export masks: 13 logical global words jj = 12*band + t, band array word
  // bmw = t + 3 (g0*8 multiple of 64 -> word-aligned). Straddle trims:
  // t==0 excludes bits 0..7 (prev band's core row), t==12 keeps only 0..7.
  if (tid < 13) {
    const int bmw = tid + 3;
    u64 m = ~0ull;
    if (tid == 0) m = ~0xFFull;
    else if (tid == 12) m = 0xFFull;
    const int eb = (zi * NBAND + band) * 16 + tid;
    expRaw[eb] = raw[1][bmw] & m;
    expUm[eb]  = Um[1][bmw] & m;
  }
}

// xy-slice thinning to convergence (dense, 512 threads), coalesced loads.
// MODE 1: slice=y (rows=z, cols=x), from maskP  -> skelY[(z*H+y)*WPR+xw]
// MODE 2: slice=x (rows=z, cols=y), from maskPX -> skelX[(z*W+x)*WPR+yw]
template<int MODE>
__device__ __forceinline__ void thin_xy(const u64* __restrict__ srcBuf,
                                        u64* __restrict__ dstBuf,
                                        int slice, u64* Abuf, u64* Bbuf,
                                        int* s_chg) {
  const int tid = threadIdx.x;
  constexpr int S = (MODE == 1) ? H : W;   // row stride multiplier

  if (tid < NXY) {
    const int rp = tid >> 3, cp = tid & 7;
    u64 v = 0;
    if (rp >= 1 && rp <= D && cp >= 1 && cp <= 6)
      v = srcBuf[((rp - 1) * S + slice) * WPR + (cp - 1)];
    Abuf[tid] = v;
    Bbuf[tid] = 0;
  }
  if (tid < 2) s_chg[tid] = 0;
  __syncthreads();

  int k = 0;
  while (true) {
    xy_dense<true >(Abuf, Bbuf, &s_chg[k], tid);
    __syncthreads();
    if (tid == 0) s_chg[k ^ 1] = 0;
    xy_dense<false>(Bbuf, Abuf, &s_chg[k], tid);
    __syncthreads();
    if (s_chg[k] == 0) break;
    k ^= 1;
  }

  if (tid < NXY) {
    const int rp = tid >> 3, cp = tid & 7;
    if (rp >= 1 && rp <= D && cp >= 1 && cp <= 6)
      dstBuf[((rp - 1) * S + slice) * WPR + (cp - 1)] = Abuf[tid];
  }
}

// K2 (512-thread blocks): b<192 -> z band phase-A; 192..575 -> x; else y.
__global__ __launch_bounds__(512) void thin_bands_xy(const u64* __restrict__ maskP,
                                                     const u64* __restrict__ maskPX,
                                                     u64* __restrict__ skelY,
                                                     u64* __restrict__ skelX,
                                                     u64* __restrict__ curZ,
                                                     u64* __restrict__ expRaw,
                                                     u64* __restrict__ expUm) {
  __shared__ u64 Abuf[(BROWS + 2) * PADW];   // 8.3 KB; xy paths use first 400
  __shared__ u64 Bbuf[(BROWS + 2) * PADW];
  __shared__ u64 raw[2][MPAD2];
  __shared__ u64 Um[2][MPAD2];
  __shared__ int s_chg[2];
  const int b = blockIdx.x;
  if (b < D * NBAND) {
    band_body(maskP, curZ, expRaw, expUm, b >> 2, b & 3, Abuf, Bbuf, raw, Um, s_chg);
  } else if (b < D * NBAND + W) {
    thin_xy<2>(maskPX, skelX, b - D * NBAND, Abuf, Bbuf, s_chg);
  } else {
    thin_xy<1>(maskP, skelY, b - D * NBAND - W, Abuf, Bbuf, s_chg);
  }
}

// K3: b<48 -> z phase-B from curZ, SEEDED with exact band change masks
// (no forced-dense passes; R18-verified). Bbuf = Abuf = S_KA: a word clean
// at subpass KA+1 has S_{KA+1}(w) = S_{KA-1}(w) = S_KA(w), so the skipped
// dst value is correct; the two-buffer invariant holds thereafter.
//     b>=48 -> skelX->skelXT ballot-transpose tiles.
__global__ __launch_bounds__(1024) void thin_z_finish(const u64* __restrict__ curZ,
                                                      u64* __restrict__ skelZ,
                                                      const u64* __restrict__ skelX,
                                                      u64* __restrict__ skelXT,
                                                      const u64* __restrict__ expRaw,
                                                      const u64* __restrict__ expUm) {
  __shared__ u64 Abuf[(H + 2) * PADW];
  __shared__ u64 Bbuf[(H + 2) * PADW];
  __shared__ u64 raw[2][MPAD2];
  __shared__ u64 Um[2][MPAD2];
  __shared__ int s_chg[2];
  const int b = blockIdx.x;
  const int tid = threadIdx.x;

  if (b < D) {
    constexpr int NP = (H + 2) * PADW;
    for (int idx = tid; idx < NP; idx += 1024) {
      const int rp = idx >> 3, cp = idx & 7;
      u64 v = 0;
      if (rp >= 1 && rp <= H && cp >= 1 && cp <= 6)
        v = curZ[(b * H + (rp - 1)) * WPR + (cp - 1)];
      Abuf[idx] = v;
      Bbuf[idx] = v;                       // MUST equal Abuf (see header comment)
    }
    // seed masks from band exports; logical word jj = j-1; main band jj/12,
    // straddle words (jj%12==0, jj>0) also OR prev band's word 12.
    if (tid < MPAD2) {
      const int j = tid, jj = j - 1;
      u64 r = 0, u = 0;
      if (jj >= 0 && jj <= 48) {
        const int bb = jj / 12, off = jj - 12 * bb;
        if (bb < NBAND) {
          r = expRaw[(b * NBAND + bb) * 16 + off];
          u = expUm[(b * NBAND + bb) * 16 + off];
        }
        if (off == 0 && jj > 0) {
          r |= expRaw[(b * NBAND + (jj / 12 - 1)) * 16 + 12];
          u |= expUm[(b * NBAND + (jj / 12 - 1)) * 16 + 12];
        }
      }
      raw[1][j] = r; Um[1][j] = u;
      raw[0][j] = 0; Um[0][j] = 0;
    }
    if (tid < 2) s_chg[tid] = 0;
    __syncthreads();

    int k = 0;
    while (true) {
      subpass<H, true, 1024 >(Abuf, Bbuf, raw[0], raw[1], Um[0], Um[1], &s_chg[k], tid);
      __syncthreads();
      if (tid == 0) s_chg[k ^ 1] = 0;
      subpass<H, false, 1024>(Bbuf, Abuf, raw[1], raw[0], Um[1], Um[0], &s_chg[k], tid);
      __syncthreads();
      if (s_chg[k] == 0) break;
      k ^= 1;
    }

    for (int idx = tid; idx < NP; idx += 1024) {
      const int rp = idx >> 3, cp = idx & 7;
      if (rp < 1 || rp > H || cp < 1 || cp > 6) continue;
      skelZ[(b * H + (rp - 1)) * WPR + (cp - 1)] = Abuf[idx];
    }
  } else {
    const int gw = (b - D) * 16 + (tid >> 6);   // tile id
    if (gw < NTILE) {
      const int lane = tid & 63;
      const int z = gw / 36, rem = gw - z * 36;
      const int yw = rem / 6, xw = rem - yw * 6;
      const int x = xw * 64 + lane;
      const u64 wx = skelX[(z * W + x) * WPR + yw];     // bits indexed by y
      u64 mine = 0;
      #pragma unroll 8
      for (int j = 0; j < 64; ++j) {
        u64 wj = __ballot((wx >> j) & 1ull);
        if (lane == j) mine = wj;
      }
      const int y = yw * 64 + lane;
      skelXT[(z * H + y) * WPR + xw] = mine;            // exclusive full coverage
    }
  }
}

// Pack mask bits (v==1.0f) along x into maskP (1728 blocks, latency-hidden).
__global__ void init_pack(const float* __restrict__ in, u64* __restrict__ maskP) {
  const int lane = threadIdx.x & 63;
  const int gwave = (blockIdx.x * blockDim.x + threadIdx.x) >> 6;
  const int nwaves = (gridDim.x * blockDim.x) >> 6;
  for (int widx = gwave; widx < NWVOL; widx += nwaves) {
    float v = in[(size_t)widx * 64 + lane];
    u64 w = __ballot(v == 1.0f);
    if (lane == 0) maskP[widx] = w;
  }
}

// Bit-transpose maskP ([z][y][xw], packed x) -> maskPX ([z][x][yw], packed y).
// One wave per 64x64 bit tile; every word written (exclusive, no init).
__global__ void transpose_in(const u64* __restrict__ maskP, u64* __restrict__ maskPX) {
  const int gw = (blockIdx.x * blockDim.x + threadIdx.x) >> 6;
  const int lane = threadIdx.x & 63;
  const int z = gw / 36, rem = gw - z * 36;
  const int yw = rem / 6, xw = rem - yw * 6;
  const u64 wp = maskP[(z * H + yw * 64 + lane) * WPR + xw];   // bits indexed by x
  u64 mine = 0;
  #pragma unroll 8
  for (int i = 0; i < 64; ++i) {
    u64 wi = __ballot((wp >> i) & 1ull);     // bit l = pixel(y=yw*64+l, x=xw*64+i)
    if (lane == i) mine = wi;
  }
  maskPX[(z * W + xw * 64 + lane) * WPR + yw] = mine;
}

// 6-connected dilation of (skelZ | skelY | skelXT) + mask + coalesced float4
// expansion. One block = 64 words = 4096 voxels.
__global__ __launch_bounds__(256) void dilate_expand(const u64* __restrict__ maskP,
                                                     const u64* __restrict__ sZ,
                                                     const u64* __restrict__ sY,
                                                     const u64* __restrict__ sXT,
                                                     float* __restrict__ out) {
  __shared__ u64 rw[64];
  const int tid = threadIdx.x;
  const int wbase = blockIdx.x * 64;
  if (tid < 64) {
    const int wi = wbase + tid;
    const int wc = wi % WPR;
    const int row = wi / WPR;        // row = z*H + y
    const int y = row % H;
    const int z = row / H;
    const u64 S = sZ[wi] | sY[wi] | sXT[wi];
    const u64 L = (wc > 0) ? (sZ[wi - 1] | sY[wi - 1] | sXT[wi - 1]) : 0ull;
    const u64 Rw = (wc < WPR - 1) ? (sZ[wi + 1] | sY[wi + 1] | sXT[wi + 1]) : 0ull;
    u64 d = S | (S << 1) | (L >> 63) | (S >> 1) | (Rw << 63);
    if (y > 0)     d |= sZ[wi - WPR] | sY[wi - WPR] | sXT[wi - WPR];
    if (y < H - 1) d |= sZ[wi + WPR] | sY[wi + WPR] | sXT[wi + WPR];
    if (z > 0)     d |= sZ[wi - H * WPR] | sY[wi - H * WPR] | sXT[wi - H * WPR];
    if (z < D - 1) d |= sZ[wi + H * WPR] | sY[wi + H * WPR] | sXT[wi + H * WPR];
    rw[tid] = d & maskP[wi];
  }
  __syncthreads();
  float4* o4 = reinterpret_cast<float4*>(out + (size_t)wbase * 64);
  #pragma unroll
  for (int k = 0; k < 4; ++k) {
    const int f = tid + 256 * k;
    const u64 bits = rw[f >> 4] >> ((f & 15) * 4);
    float4 o;
    o.x = (float)(bits & 1ull);
    o.y = (float)((bits >> 1) & 1ull);
    o.z = (float)((bits >> 2) & 1ull);
    o.w = (float)((bits >> 3) & 1ull);
    o4[f] = o;
  }
}

extern "C" void kernel_launch(void* const* d_in, const int* in_sizes, int n_in,
                              void* d_out, int out_size, void* d_ws, size_t ws_size,
                              hipStream_t stream) {
  const float* in = (const float*)d_in[0];
  float* out = (float*)d_out;
  u64* wsw = (u64*)d_ws;                 // 7*NWVOL + 2*192*16 u64 = 6.24 MB
  u64* maskP = wsw;
  u64* maskPX = wsw + NWVOL;
  u64* skelZ = wsw + 2 * NWVOL;
  u64* skelY = wsw + 3 * NWVOL;
  u64* skelX = wsw + 4 * NWVOL;
  u64* skelXT = wsw + 5 * NWVOL;
  u64* curZ = wsw + 6 * NWVOL;
  u64* expRaw = wsw + 7 * NWVOL;
  u64* expUm = expRaw + 192 * 16;

  init_pack<<<1728, 256, 0, stream>>>(in, maskP);
  transpose_in<<<(NTILE * 64) / 256, 256, 0, stream>>>(maskP, maskPX);
  thin_bands_xy<<<D * NBAND + W + H, 512, 0, stream>>>(maskP, maskPX, skelY, skelX,
                                                       curZ, expRaw, expUm);
  thin_z_finish<<<D + (NTILE + 15) / 16, 1024, 0, stream>>>(curZ, skelZ, skelX, skelXT,
                                                            expRaw, expUm);
  dilate_expand<<<NWVOL / 64, 256, 0, stream>>>(maskP, skelZ, skelY, skelXT, out);
}